// Round 1
// baseline (189.580 us; speedup 1.0000x reference)
//
#include <hip/hip_runtime.h>
#include <math.h>

#define NANCH 2
#define NCLS  20
#define HH 7
#define WW 7
#define NBOX 98            // 7*7*2
#define ROWLEN 1470        // 7*7*30
#define NMS_T 0.7f
#define SCORE_T 0.05f

__device__ __forceinline__ float sigm(float v) {
    return 1.0f / (1.0f + expf(-v));
}

__global__ __launch_bounds__(128) void yolo_post(const float* __restrict__ x,
                                                 float* __restrict__ out,
                                                 int batch) {
    const int b   = blockIdx.x;
    const int tid = threadIdx.x;

    __shared__ float row[ROWLEN];
    __shared__ float key[NBOX];
    __shared__ float ux1[NBOX], uy1[NBOX], ux2[NBOX], uy2[NBOX];
    __shared__ float usc[NBOX];
    __shared__ int   ulab[NBOX];
    __shared__ int   uval[NBOX];
    __shared__ float sx1[NBOX], sy1[NBOX], sx2[NBOX], sy2[NBOX], ssc[NBOX];
    __shared__ int   slab[NBOX], sval[NBOX];
    __shared__ unsigned long long m0[NBOX], m1[NBOX];
    __shared__ unsigned long long aliveW[2];

    // ---- stage input row ----
    const float* xr = x + (size_t)b * ROWLEN;
    for (int idx = tid; idx < ROWLEN; idx += 128) row[idx] = xr[idx];
    __syncthreads();

    // ---- decode box tid ----
    if (tid < NBOX) {
        const int k  = tid >> 1;          // cell 0..48
        const int a  = tid & 1;           // anchor
        const int ci = k / WW;            // row i
        const int cj = k - ci * WW;       // col j
        const float* p = row + k * 30 + a * 5;
        const float bx = sigm(p[0]) + (float)cj * 64.0f;
        const float by = sigm(p[1]) + (float)ci * 64.0f;
        const float bw = sigm(p[2]);
        const float bh = sigm(p[3]);
        const int valid = (p[4] >= 0.0f) ? 1 : 0;   // sigmoid(o)>=0.5 <=> o>=0

        // first-occurrence argmax over 20 class logits (shared per cell)
        const float* c = row + k * 30 + 10;
        float mx = c[0]; int ml = 0;
        #pragma unroll
        for (int t = 1; t < NCLS; ++t) {
            float v = c[t];
            if (v > mx) { mx = v; ml = t; }
        }

        ux1[tid] = fminf(fmaxf(bx, 0.0f), 1.0f);
        uy1[tid] = fminf(fmaxf(by, 0.0f), 1.0f);
        ux2[tid] = fminf(fmaxf(bx + bw, 0.0f), 1.0f);
        uy2[tid] = fminf(fmaxf(by + bh, 0.0f), 1.0f);
        usc[tid] = mx;
        ulab[tid] = ml;
        uval[tid] = valid;
        key[tid] = valid ? mx : -INFINITY;
    }
    __syncthreads();

    // ---- stable descending rank sort (matches jnp.argsort(-s), stable) ----
    if (tid < NBOX) {
        const float ki = key[tid];
        int rank = 0;
        for (int j = 0; j < NBOX; ++j) {
            const float kj = key[j];
            rank += (kj > ki) || ((kj == ki) && (j < tid));
        }
        sx1[rank] = ux1[tid]; sy1[rank] = uy1[tid];
        sx2[rank] = ux2[tid]; sy2[rank] = uy2[tid];
        ssc[rank] = usc[tid]; slab[rank] = ulab[tid];
        sval[rank] = uval[tid];
    }
    __syncthreads();

    // ---- per-row suppression masks: bit j set iff j>i and iou(i,j)>0.7 ----
    if (tid < NBOX) {
        const float x1 = sx1[tid], y1 = sy1[tid];
        const float x2 = sx2[tid], y2 = sy2[tid];
        const float area_i = (x2 - x1) * (y2 - y1);
        unsigned long long mm0 = 0ull, mm1 = 0ull;
        for (int j = tid + 1; j < NBOX; ++j) {
            const float jx1 = sx1[j], jy1 = sy1[j], jx2 = sx2[j], jy2 = sy2[j];
            const float ltx = fmaxf(x1, jx1);
            const float lty = fmaxf(y1, jy1);
            const float rbx = fminf(x2, jx2);
            const float rby = fminf(y2, jy2);
            const float w = fmaxf(rbx - ltx, 0.0f);
            const float h = fmaxf(rby - lty, 0.0f);
            const float inter = w * h;
            const float area_j = (jx2 - jx1) * (jy2 - jy1);
            const float uni = (area_i + area_j) - inter;   // same op order as ref
            const float iou = (uni > 0.0f) ? (inter / uni) : 0.0f;
            if (iou > NMS_T) {
                if (j < 64) mm0 |= (1ull << j);
                else        mm1 |= (1ull << (j - 64));
            }
        }
        m0[tid] = mm0; m1[tid] = mm1;
    }
    __syncthreads();

    // ---- sequential greedy NMS sweep (single thread, ~100 iters of bit ops) ----
    if (tid == 0) {
        unsigned long long a0 = 0ull, a1 = 0ull;
        for (int j = 0; j < 64; ++j)  a0 |= ((unsigned long long)(sval[j] & 1)) << j;
        for (int j = 64; j < NBOX; ++j) a1 |= ((unsigned long long)(sval[j] & 1)) << (j - 64);
        for (int i = 0; i < 64; ++i) {
            if ((a0 >> i) & 1ull) { a0 &= ~m0[i]; a1 &= ~m1[i]; }
        }
        for (int i = 64; i < NBOX; ++i) {
            if ((a1 >> (i - 64)) & 1ull) { a1 &= ~m1[i]; }   // m0[i] only has bits j>i>=64 -> none in word0
        }
        aliveW[0] = a0; aliveW[1] = a1;
    }
    __syncthreads();

    // ---- outputs: boxes [b,98,4], scores [b,98], labels [b,98], keep [b,98] ----
    if (tid < NBOX) {
        const bool al = (tid < 64) ? ((aliveW[0] >> tid) & 1ull)
                                   : ((aliveW[1] >> (tid - 64)) & 1ull);
        const bool kept = al && (ssc[tid] >= SCORE_T);

        float4 bo;
        if (kept) { bo.x = sx1[tid]; bo.y = sy1[tid]; bo.z = sx2[tid]; bo.w = sy2[tid]; }
        else      { bo.x = 0.0f; bo.y = 0.0f; bo.z = 0.0f; bo.w = 0.0f; }
        // byte offset b*1568 + tid*16 -> 16B aligned
        *reinterpret_cast<float4*>(out + (size_t)b * (NBOX * 4) + (size_t)tid * 4) = bo;

        const size_t base1 = (size_t)batch * (NBOX * 4);
        const size_t base2 = base1 + (size_t)batch * NBOX;
        const size_t base3 = base2 + (size_t)batch * NBOX;
        out[base1 + (size_t)b * NBOX + tid] = kept ? ssc[tid] : 0.0f;
        out[base2 + (size_t)b * NBOX + tid] = kept ? (float)slab[tid] : 0.0f;
        out[base3 + (size_t)b * NBOX + tid] = kept ? 1.0f : 0.0f;
    }
}

extern "C" void kernel_launch(void* const* d_in, const int* in_sizes, int n_in,
                              void* d_out, int out_size, void* d_ws, size_t ws_size,
                              hipStream_t stream) {
    const float* x = (const float*)d_in[0];
    float* out = (float*)d_out;
    const int batch = in_sizes[0] / ROWLEN;   // 8192
    yolo_post<<<batch, 128, 0, stream>>>(x, out, batch);
}

// Round 2
// 118.244 us; speedup vs baseline: 1.6033x; 1.6033x over previous
//
#include <hip/hip_runtime.h>
#include <math.h>

#define NBOX 98            // 7*7*2
#define ROWLEN 1470        // 7*7*30
#define NMS_T 0.7f
#define SCORE_T 0.05f

__device__ __forceinline__ float sigm(float v) {
    return 1.0f / (1.0f + expf(-v));
}

__global__ __launch_bounds__(128) void yolo_post(const float* __restrict__ x,
                                                 float* __restrict__ out,
                                                 int batch) {
    const int b    = blockIdx.x;
    const int tid  = threadIdx.x;
    const int wid  = tid >> 6;
    const int lane = tid & 63;

    __shared__ float  row[ROWLEN];
    __shared__ float  cscore[NBOX];           // compacted (valid-only) scores, original order
    __shared__ float4 sbox[NBOX];             // sorted boxes (xyxy, clamped)
    __shared__ float  sarea[NBOX];
    __shared__ float  ssc[NBOX];
    __shared__ int    slab[NBOX];
    __shared__ unsigned long long m0[NBOX], m1[NBOX];
    __shared__ unsigned long long aliveW[2];
    __shared__ int    sCnt[2];

    // ---- stage input row (float2, coalesced; row byte base b*5880 is 8B aligned) ----
    const float2* xr2 = reinterpret_cast<const float2*>(x + (size_t)b * ROWLEN);
    float2* row2 = reinterpret_cast<float2*>(row);
    for (int i = tid; i < ROWLEN / 2; i += 128) row2[i] = xr2[i];
    __syncthreads();

    // ---- decode box tid into registers ----
    float4 box = make_float4(0.f, 0.f, 0.f, 0.f);
    float  mx  = 0.f;
    int    ml  = 0;
    bool   valid = false;
    if (tid < NBOX) {
        const int k  = tid >> 1;          // cell
        const int a  = tid & 1;           // anchor
        const int ci = k / 7;
        const int cj = k - ci * 7;
        const float* p = row + k * 30 + a * 5;
        const float bx = sigm(p[0]) + (float)cj * 64.0f;
        const float by = sigm(p[1]) + (float)ci * 64.0f;
        const float bw = sigm(p[2]);
        const float bh = sigm(p[3]);
        valid = (p[4] >= 0.0f);           // sigmoid(o) >= 0.5  <=>  o >= 0

        const float* c = row + k * 30 + 10;
        mx = c[0]; ml = 0;
        #pragma unroll
        for (int t = 1; t < 20; ++t) {
            float v = c[t];
            if (v > mx) { mx = v; ml = t; }
        }
        box.x = fminf(fmaxf(bx, 0.f), 1.f);
        box.y = fminf(fmaxf(by, 0.f), 1.f);
        box.z = fminf(fmaxf(bx + bw, 0.f), 1.f);
        box.w = fminf(fmaxf(by + bh, 0.f), 1.f);
    }

    // ---- compact valid boxes (order-preserving) via ballot ----
    const unsigned long long bal = __ballot(valid);
    if (lane == 0) sCnt[wid] = (int)__popcll(bal);
    __syncthreads();
    const int V = sCnt[0] + sCnt[1];
    const int c = (int)__popcll(bal & ((1ull << lane) - 1ull)) + (wid ? sCnt[0] : 0);
    if (valid) cscore[c] = mx;
    __syncthreads();

    // ---- stable descending rank among valid (ties -> original order) + scatter ----
    if (valid) {
        int rank = 0;
        for (int j = 0; j < V; ++j) {
            const float kj = cscore[j];            // broadcast read
            rank += (kj > mx) || ((kj == mx) && (j < c));
        }
        sbox[rank]  = box;
        sarea[rank] = (box.z - box.x) * (box.w - box.y);
        ssc[rank]   = mx;
        slab[rank]  = ml;
    }
    __syncthreads();

    // ---- suppression masks: row i, bit j set iff j>i and iou(i,j) > 0.7 ----
    // uniform full-row loop: all lanes read the same j -> LDS broadcast, no conflicts
    if (tid < V) {
        const float4 bi = sbox[tid];
        const float  ai = sarea[tid];
        unsigned long long mm0 = 0ull, mm1 = 0ull;
        const int e0 = (V < 64) ? V : 64;
        unsigned long long bit = 1ull;
        for (int j = 0; j < e0; ++j, bit <<= 1) {
            const float4 bj = sbox[j];
            const float w = fmaxf(fminf(bi.z, bj.z) - fmaxf(bi.x, bj.x), 0.f);
            const float h = fmaxf(fminf(bi.w, bj.w) - fmaxf(bi.y, bj.y), 0.f);
            const float inter = w * h;
            const float uni = (ai + sarea[j]) - inter;    // ref op order
            if (uni > 0.f && inter > NMS_T * uni) mm0 |= bit;
        }
        if (V > 64) {
            bit = 1ull;
            for (int j = 64; j < V; ++j, bit <<= 1) {
                const float4 bj = sbox[j];
                const float w = fmaxf(fminf(bi.z, bj.z) - fmaxf(bi.x, bj.x), 0.f);
                const float h = fmaxf(fminf(bi.w, bj.w) - fmaxf(bi.y, bj.y), 0.f);
                const float inter = w * h;
                const float uni = (ai + sarea[j]) - inter;
                if (uni > 0.f && inter > NMS_T * uni) mm1 |= bit;
            }
        }
        // keep only bits j > tid
        if (tid < 64) {
            mm0 &= ~((2ull << tid) - 1ull);   // tid==63 -> mask=~0 -> mm0=0 (2ull<<63 wraps to 0)
        } else {
            mm0 = 0ull;
            mm1 &= ~((2ull << (tid - 64)) - 1ull);
        }
        m0[tid] = mm0;
        m1[tid] = mm1;
    }
    __syncthreads();

    // ---- greedy sweep (serial, over V valid bits; all V boxes start alive) ----
    if (tid == 0) {
        if (V <= 64) {
            unsigned long long a0 = (V == 64) ? ~0ull : ((1ull << V) - 1ull);
            for (int i = 0; i < V; ++i)
                if ((a0 >> i) & 1ull) a0 &= ~m0[i];
            aliveW[0] = a0; aliveW[1] = 0ull;
        } else {
            unsigned long long a0 = ~0ull;
            unsigned long long a1 = (1ull << (V - 64)) - 1ull;
            for (int i = 0; i < 64; ++i)
                if ((a0 >> i) & 1ull) { a0 &= ~m0[i]; a1 &= ~m1[i]; }
            for (int i = 64; i < V; ++i)
                if ((a1 >> (i - 64)) & 1ull) a1 &= ~m1[i];
            aliveW[0] = a0; aliveW[1] = a1;
        }
    }
    __syncthreads();

    // ---- outputs: boxes [b,98,4] | scores [b,98] | labels [b,98] | keep [b,98] ----
    if (tid < NBOX) {
        float4 bo = make_float4(0.f, 0.f, 0.f, 0.f);
        float so = 0.f, lo = 0.f, ko = 0.f;
        if (tid < V) {
            const bool al = (tid < 64) ? ((aliveW[0] >> tid) & 1ull)
                                       : ((aliveW[1] >> (tid - 64)) & 1ull);
            const float s = ssc[tid];
            if (al && s >= SCORE_T) {
                bo = sbox[tid]; so = s; lo = (float)slab[tid]; ko = 1.0f;
            }
        }
        *reinterpret_cast<float4*>(out + (size_t)b * (NBOX * 4) + (size_t)tid * 4) = bo;
        const size_t base1 = (size_t)batch * (NBOX * 4);
        const size_t bn    = (size_t)batch * NBOX;
        out[base1 +          (size_t)b * NBOX + tid] = so;
        out[base1 + bn +     (size_t)b * NBOX + tid] = lo;
        out[base1 + 2 * bn + (size_t)b * NBOX + tid] = ko;
    }
}

extern "C" void kernel_launch(void* const* d_in, const int* in_sizes, int n_in,
                              void* d_out, int out_size, void* d_ws, size_t ws_size,
                              hipStream_t stream) {
    const float* x = (const float*)d_in[0];
    float* out = (float*)d_out;
    const int batch = in_sizes[0] / ROWLEN;   // 8192
    yolo_post<<<batch, 128, 0, stream>>>(x, out, batch);
}